// Round 1
// baseline (530.621 us; speedup 1.0000x reference)
//
#include <hip/hip_runtime.h>
#include <cstdint>
#include <cstddef>

#define DD 256
#define TILE_M 64

typedef unsigned short u16;
typedef __bf16 bf16t;
typedef bf16t bf16x8 __attribute__((ext_vector_type(8)));
typedef unsigned short us8 __attribute__((ext_vector_type(8)));
typedef float f32x4 __attribute__((ext_vector_type(4)));

__device__ __forceinline__ u16 f2bf(float f) {
    uint32_t u = __builtin_bit_cast(uint32_t, f);
    u += 0x7FFFu + ((u >> 16) & 1u);   // RNE
    return (u16)(u >> 16);
}

__global__ void k_convert(const float* __restrict__ s, u16* __restrict__ d, int n) {
    int i = blockIdx.x * blockDim.x + threadIdx.x;
    int st = gridDim.x * blockDim.x;
    for (; i < n; i += st) d[i] = f2bf(s[i]);
}

__global__ void k_zero(int* p, int n) {
    int i = blockIdx.x * blockDim.x + threadIdx.x;
    if (i < n) p[i] = 0;
}

__global__ void k_hist(const int* __restrict__ rel, int E, int R, int* __restrict__ counts) {
    __shared__ int h[32];
    if (threadIdx.x < 32) h[threadIdx.x] = 0;
    __syncthreads();
    int i = blockIdx.x * blockDim.x + threadIdx.x;
    int st = gridDim.x * blockDim.x;
    for (; i < E; i += st) atomicAdd(&h[rel[i]], 1);
    __syncthreads();
    if (threadIdx.x < R && h[threadIdx.x]) atomicAdd(&counts[threadIdx.x], h[threadIdx.x]);
}

__global__ void k_scan(const int* __restrict__ counts, int R, int* __restrict__ offs,
                       int* __restrict__ cursor, int* __restrict__ toffs) {
    if (threadIdx.x == 0 && blockIdx.x == 0) {
        int s = 0, t = 0;
        for (int r = 0; r < R; ++r) {
            offs[r] = s; cursor[r] = s; toffs[r] = t;
            s += counts[r];
            t += (counts[r] + TILE_M - 1) / TILE_M;
        }
        offs[R] = s; toffs[R] = t;
    }
}

// counting-sort scatter with per-block LDS aggregation (order within bucket irrelevant)
__global__ void k_scatter(const int* __restrict__ rel, int E, int R,
                          int* __restrict__ cursor, int* __restrict__ sorted) {
    __shared__ int h[32], basearr[32];
    int chunk = (E + gridDim.x - 1) / gridDim.x;
    int lo = blockIdx.x * chunk;
    int hi = min(lo + chunk, E);
    if (threadIdx.x < 32) h[threadIdx.x] = 0;
    __syncthreads();
    for (int i = lo + threadIdx.x; i < hi; i += blockDim.x) atomicAdd(&h[rel[i]], 1);
    __syncthreads();
    if (threadIdx.x < R) {
        basearr[threadIdx.x] = atomicAdd(&cursor[threadIdx.x], h[threadIdx.x]);
        h[threadIdx.x] = 0;
    }
    __syncthreads();
    for (int i = lo + threadIdx.x; i < hi; i += blockDim.x) {
        int r = rel[i];
        int p = basearr[r] + atomicAdd(&h[r], 1);
        sorted[p] = i;
    }
}

// GEMM: out-tile = A(gathered rows of xb) @ W^T + bias
// GATHER=true : A rows = x[src[e]] for edges of one (relation, direction); atomicAdd into out[dst[e]]
// GATHER=false: A rows = x[i] (self transform); plain store
template <bool GATHER>
__global__ __launch_bounds__(256)
void k_gemm(const u16* __restrict__ xb, const u16* __restrict__ Wb,
            const float* __restrict__ bias_all,
            const int* __restrict__ dep, const int* __restrict__ gov,
            const int* __restrict__ sorted, const int* __restrict__ offs,
            const int* __restrict__ toffs,
            float* __restrict__ out, int Rq, int Nrows) {
    __shared__ u16 As[TILE_M][72];   // 64 rows x BK=64, padded to 72 (bank-balanced b128)
    __shared__ u16 Bs[DD][72];       // 256 W-rows x BK=64, padded
    __shared__ int s_src[TILE_M], s_dst[TILE_M];

    int row0, cnt, base, wmat;
    const float* bias;
    if constexpr (GATHER) {
        int b = blockIdx.x;
        if (b >= toffs[Rq]) return;          // uniform exit before any barrier
        int r = 0;
        while (r + 1 < Rq && toffs[r + 1] <= b) ++r;
        int tile = b - toffs[r];
        base = offs[r];
        cnt  = offs[r + 1] - base;
        row0 = tile * TILE_M;
        wmat = r + (int)blockIdx.z * Rq;     // dir=1 -> reversed-label weights
        bias = bias_all + (size_t)wmat * DD;
    } else {
        row0 = blockIdx.x * TILE_M;
        base = 0; cnt = Nrows;
        wmat = 2 * Rq;                       // W_self slot
        bias = bias_all;
    }

    int tid = threadIdx.x;
    if (tid < TILE_M) {
        int i = row0 + tid;
        bool valid = i < cnt;
        int src, dst;
        if constexpr (GATHER) {
            int e = sorted[base + (valid ? i : 0)];
            int dir = blockIdx.z;
            src = dir ? dep[e] : gov[e];
            dst = dir ? gov[e] : dep[e];
        } else {
            src = valid ? i : 0;
            dst = i;
        }
        s_src[tid] = src;
        s_dst[tid] = valid ? dst : -1;
    }
    __syncthreads();

    f32x4 acc[4][4] = {};
    int lane = tid & 63;
    int wave = tid >> 6;          // wave w owns output cols [64w, 64w+64)
    int l15  = lane & 15;
    int quad = lane >> 4;

    const u16* wbase = Wb + (size_t)wmat * (DD * DD);

    for (int kt = 0; kt < 4; ++kt) {         // K = 256 in BK=64 steps
        int k0 = kt * 64;
        {   // stage A: 64 rows x 64 bf16; thread t -> row t/4, 32B chunk t%4
            int m = tid >> 2, c = tid & 3;
            const u16* gp = xb + (size_t)s_src[m] * DD + k0 + c * 16;
            *(us8*)&As[m][c * 16]     = *(const us8*)gp;
            *(us8*)&As[m][c * 16 + 8] = *(const us8*)(gp + 8);
        }
        {   // stage B: W rows as-is (Bs[n][k] = W[n][k0+k]); thread t -> W row t
            const u16* gp = wbase + (size_t)tid * DD + k0;
            #pragma unroll
            for (int c = 0; c < 8; ++c)
                *(us8*)&Bs[tid][c * 8] = *(const us8*)(gp + c * 8);
        }
        __syncthreads();
        #pragma unroll
        for (int ks = 0; ks < 2; ++ks) {     // two K=32 mfma steps per staged BK=64
            int kk = ks * 32 + quad * 8;
            bf16x8 af[4], bfr[4];
            #pragma unroll
            for (int mt = 0; mt < 4; ++mt)
                af[mt] = __builtin_bit_cast(bf16x8, *(const us8*)&As[mt * 16 + l15][kk]);
            #pragma unroll
            for (int nt = 0; nt < 4; ++nt)
                bfr[nt] = __builtin_bit_cast(bf16x8, *(const us8*)&Bs[wave * 64 + nt * 16 + l15][kk]);
            #pragma unroll
            for (int mt = 0; mt < 4; ++mt)
                #pragma unroll
                for (int nt = 0; nt < 4; ++nt)
                    acc[mt][nt] = __builtin_amdgcn_mfma_f32_16x16x32_bf16(
                        af[mt], bfr[nt], acc[mt][nt], 0, 0, 0);
        }
        __syncthreads();
    }

    // epilogue: C/D layout col=lane&15, row=quad*4+reg (verified m89/m91)
    #pragma unroll
    for (int nt = 0; nt < 4; ++nt) {
        int n = wave * 64 + nt * 16 + l15;
        float bv = bias[n];
        #pragma unroll
        for (int mt = 0; mt < 4; ++mt) {
            #pragma unroll
            for (int j = 0; j < 4; ++j) {
                int m = mt * 16 + quad * 4 + j;
                int dst = s_dst[m];
                if (dst >= 0) {
                    float v = acc[mt][nt][j] + bv;
                    if constexpr (GATHER)
                        atomicAdd(out + (size_t)dst * DD + n, v);
                    else
                        out[(size_t)dst * DD + n] = v;
                }
            }
        }
    }
}

__global__ void k_relu(float* __restrict__ p, int n) {
    int i = blockIdx.x * blockDim.x + threadIdx.x;
    int st = gridDim.x * blockDim.x;
    for (; i < n; i += st) p[i] = fmaxf(p[i], 0.0f);
}

extern "C" void kernel_launch(void* const* d_in, const int* in_sizes, int n_in,
                              void* d_out, int out_size, void* d_ws, size_t ws_size,
                              hipStream_t stream) {
    const float* x      = (const float*)d_in[0];
    const int*   dep    = (const int*)  d_in[1];
    const int*   rel    = (const int*)  d_in[2];
    const int*   gov    = (const int*)  d_in[3];
    const float* W_self = (const float*)d_in[4];
    const float* b_self = (const float*)d_in[5];
    const float* W_rel  = (const float*)d_in[6];
    const float* b_rel  = (const float*)d_in[7];
    float* out = (float*)d_out;

    const int N  = in_sizes[0] / DD;     // 20000
    const int E  = in_sizes[1];          // 200000
    const int R2 = in_sizes[7] / DD;     // 24
    const int R  = R2 / 2;               // 12

    // workspace layout (~15 MB total)
    char* w = (char*)d_ws;
    auto alloc = [&](size_t bytes) {
        char* p = w;
        w += (bytes + 255) & ~(size_t)255;
        return p;
    };
    u16* xb     = (u16*)alloc((size_t)N * DD * sizeof(u16));
    u16* Wb     = (u16*)alloc((size_t)(R2 + 1) * DD * DD * sizeof(u16));
    int* counts = (int*)alloc((size_t)R * sizeof(int));
    int* offs   = (int*)alloc((size_t)(R + 1) * sizeof(int));
    int* cursor = (int*)alloc((size_t)R * sizeof(int));
    int* toffs  = (int*)alloc((size_t)(R + 1) * sizeof(int));
    int* sorted = (int*)alloc((size_t)E * sizeof(int));

    // 1. bf16 conversions (x, W_rel, W_self)
    k_convert<<<1024, 256, 0, stream>>>(x, xb, N * DD);
    k_convert<<<1024, 256, 0, stream>>>(W_rel, Wb, R2 * DD * DD);
    k_convert<<<64, 256, 0, stream>>>(W_self, Wb + (size_t)R2 * DD * DD, DD * DD);

    // 2. bucket edges by relation label
    k_zero<<<1, 64, 0, stream>>>(counts, R);
    k_hist<<<256, 256, 0, stream>>>(rel, E, R, counts);
    k_scan<<<1, 64, 0, stream>>>(counts, R, offs, cursor, toffs);
    k_scatter<<<128, 256, 0, stream>>>(rel, E, R, cursor, sorted);

    // 3. self transform (initializes all of out; plain stores)
    int selfGrid = (N + TILE_M - 1) / TILE_M;
    k_gemm<false><<<dim3(selfGrid, 1, 1), 256, 0, stream>>>(
        xb, Wb, b_self, nullptr, nullptr, nullptr, nullptr, nullptr, out, R, N);

    // 4. edge messages: grouped GEMM per (relation, direction), atomic scatter-add
    int maxTiles = (E + TILE_M - 1) / TILE_M + R;   // upper bound on toffs[R]
    k_gemm<true><<<dim3(maxTiles, 1, 2), 256, 0, stream>>>(
        xb, Wb, b_rel, dep, gov, sorted, offs, toffs, out, R, 0);

    // 5. relu
    k_relu<<<1024, 256, 0, stream>>>(out, out_size);
}